// Round 1
// baseline (3281.083 us; speedup 1.0000x reference)
//
#include <hip/hip_runtime.h>
#include <hip/hip_bf16.h>
#include <cstdint>

// BLSTM: B=32, T=1024, D=256, U=256. Gate order i,f,c,o. fwd = cols [0,4U), bwd = cols [4U,8U).
#define B_ 32
#define T_ 1024
#define D_ 256
#define U_ 256

typedef _Float16 f16;
typedef _Float16 f16x2 __attribute__((ext_vector_type(2)));
typedef _Float16 f16x4 __attribute__((ext_vector_type(4)));
typedef _Float16 f16x8 __attribute__((ext_vector_type(8)));
typedef float f32x4 __attribute__((ext_vector_type(4)));

static __device__ __forceinline__ f16x2 u2h(uint32_t u) {
    return __builtin_bit_cast(f16x2, u);
}

static __device__ __forceinline__ float hsig(float v) {
    return fminf(fmaxf(fmaf(v, 0.2f, 0.5f), 0.0f), 1.0f);
}

static __device__ __forceinline__ float tanh_f(float x) {
    // tanh(x) = 1 - 2/(exp(2x)+1); handles +-inf correctly
    float e = __expf(2.0f * x);
    return 1.0f - 2.0f / (e + 1.0f);
}

// ---- prep: convert x [B*T*D] f32 -> f16 ----
__global__ void convert_x(const float* __restrict__ x, f16* __restrict__ xh) {
    int i = blockIdx.x * blockDim.x + threadIdx.x;  // over 8388608/4 elems
    float4 v = ((const float4*)x)[i];
    f16x4 o;
    o[0] = (f16)v.x; o[1] = (f16)v.y; o[2] = (f16)v.z; o[3] = (f16)v.w;
    ((f16x4*)xh)[i] = o;
}

// ---- prep: transpose [256][2048] f32 -> [2048][256] f16 ----
__global__ void transpose_to_f16(const float* __restrict__ in, f16* __restrict__ out) {
    // one block per output row g (2048 blocks, 256 threads)
    int g = blockIdx.x;
    int k = threadIdx.x;
    out[g * 256 + k] = (f16)in[k * 2048 + g];
}

// ---- phase 1: xg[t][b][g] = sum_d x[b][t][d] * kernel[d][g]  (MFMA, LDS-free) ----
__global__ __launch_bounds__(256) void gemm_xk(const f16* __restrict__ A,   // [32768][256] row r=b*1024+t
                                               const f16* __restrict__ Bt,  // [2048][256]
                                               f16* __restrict__ xg) {      // [1024][32][2048]
    int nb = blockIdx.x;  // 0..15 col-block (128 cols)
    int mb = blockIdx.y;  // 0..255 row-block (128 rows)
    int tid = threadIdx.x;
    int l = tid & 63, w = tid >> 6;
    int wr = w >> 1, wc = w & 1;
    int row0 = mb * 128 + wr * 64;
    int col0 = nb * 128 + wc * 64;
    int lr = l & 15, lk = (l >> 4) * 8;

    f32x4 acc[4][4] = {};
    for (int k0 = 0; k0 < 256; k0 += 32) {
        f16x8 af[4], bf[4];
#pragma unroll
        for (int mi = 0; mi < 4; mi++)
            af[mi] = *(const f16x8*)&A[(row0 + mi * 16 + lr) * 256 + k0 + lk];
#pragma unroll
        for (int ni = 0; ni < 4; ni++)
            bf[ni] = *(const f16x8*)&Bt[(col0 + ni * 16 + lr) * 256 + k0 + lk];
#pragma unroll
        for (int mi = 0; mi < 4; mi++)
#pragma unroll
            for (int ni = 0; ni < 4; ni++)
                acc[mi][ni] = __builtin_amdgcn_mfma_f32_16x16x32_f16(af[mi], bf[ni], acc[mi][ni], 0, 0, 0);
    }
    // C/D layout: col = lane&15, row = (lane>>4)*4 + q  (m89-verified, dtype-independent)
#pragma unroll
    for (int mi = 0; mi < 4; mi++) {
#pragma unroll
        for (int q = 0; q < 4; q++) {
            int row = row0 + mi * 16 + (l >> 4) * 4 + q;
            int b = row >> 10, t = row & 1023;
            long obase = (long)((t << 5) + b) * 2048;
#pragma unroll
            for (int ni = 0; ni < 4; ni++) {
                int col = col0 + ni * 16 + lr;
                xg[obase + col] = (f16)acc[mi][ni][q];
            }
        }
    }
}

// ---- phase 2: recurrence. One workgroup per (direction, batch). Weights in VGPRs. ----
__global__ __launch_bounds__(512, 1) void blstm_rec(const f16* __restrict__ xg,      // [1024][32][2048]
                                                    const uint32_t* __restrict__ wt, // [2048][128] f16-pairs over k
                                                    float* __restrict__ out) {       // [32][1024][512]
    __shared__ float g_lds[1024];
    __shared__ __align__(16) f16 h_lds[256];

    int bid = blockIdx.x;
    int d = bid >> 5;   // direction
    int b = bid & 31;   // batch
    int j = threadIdx.x;  // 0..511; owns gate-cols j and j+512

    // load recurrent weights into registers: 2 cols x 128 f16-pairs
    uint32_t w0[128], w1[128];
    {
        const uint32_t* p0 = wt + (size_t)((d << 10) + j) * 128;
        const uint32_t* p1 = wt + (size_t)((d << 10) + 512 + j) * 128;
#pragma unroll
        for (int kk = 0; kk < 128; kk++) { w0[kk] = p0[kk]; w1[kk] = p1[kk]; }
    }

    float c = 0.0f;
    if (j < 256) h_lds[j] = (f16)0.0f;
    __syncthreads();

    const int dbase = d << 10;
    float a0, a1;
    {
        int t0 = d ? (T_ - 1) : 0;
        const f16* xp = xg + (size_t)((t0 << 5) + b) * 2048 + dbase;
        a0 = (float)xp[j];
        a1 = (float)xp[512 + j];
    }

    for (int s = 0; s < T_; ++s) {
        int t = d ? (T_ - 1 - s) : s;
        // prefetch next step's xg (independent of h -> hides HBM latency under the dots)
        float na0 = 0.0f, na1 = 0.0f;
        if (s + 1 < T_) {
            int tn = d ? (T_ - 2 - s) : (s + 1);
            const f16* xp = xg + (size_t)((tn << 5) + b) * 2048 + dbase;
            na0 = (float)xp[j];
            na1 = (float)xp[512 + j];
        }

        float acc0 = a0, acc1 = a1;
        const uint4* hq = (const uint4*)h_lds;  // broadcast reads (all lanes same addr: conflict-free)
#pragma unroll
        for (int i = 0; i < 32; i++) {
            uint4 q = hq[i];
            acc0 = __builtin_amdgcn_fdot2(u2h(q.x), u2h(w0[4 * i + 0]), acc0, false);
            acc0 = __builtin_amdgcn_fdot2(u2h(q.y), u2h(w0[4 * i + 1]), acc0, false);
            acc0 = __builtin_amdgcn_fdot2(u2h(q.z), u2h(w0[4 * i + 2]), acc0, false);
            acc0 = __builtin_amdgcn_fdot2(u2h(q.w), u2h(w0[4 * i + 3]), acc0, false);
            acc1 = __builtin_amdgcn_fdot2(u2h(q.x), u2h(w1[4 * i + 0]), acc1, false);
            acc1 = __builtin_amdgcn_fdot2(u2h(q.y), u2h(w1[4 * i + 1]), acc1, false);
            acc1 = __builtin_amdgcn_fdot2(u2h(q.z), u2h(w1[4 * i + 2]), acc1, false);
            acc1 = __builtin_amdgcn_fdot2(u2h(q.w), u2h(w1[4 * i + 3]), acc1, false);
        }
        g_lds[j] = acc0;
        g_lds[512 + j] = acc1;
        __syncthreads();

        if (j < 256) {
            float gi = g_lds[j];
            float gf = g_lds[256 + j];
            float gm = g_lds[512 + j];
            float go = g_lds[768 + j];
            float i_ = hsig(gi), f_ = hsig(gf), m_ = tanh_f(gm), o_ = hsig(go);
            c = f_ * c + i_ * m_;
            float h = o_ * tanh_f(c);
            out[(size_t)((b << 10) + t) * 512 + (d << 8) + j] = h;
            h_lds[j] = (f16)h;
        }
        __syncthreads();

        a0 = na0;
        a1 = na1;
    }
}

extern "C" void kernel_launch(void* const* d_in, const int* in_sizes, int n_in,
                              void* d_out, int out_size, void* d_ws, size_t ws_size,
                              hipStream_t stream) {
    const float* x = (const float*)d_in[0];       // [32][1024][256]
    const float* kern = (const float*)d_in[1];    // [256][2048]
    const float* rk = (const float*)d_in[2];      // [256][2048]
    float* out = (float*)d_out;                   // [32][1024][512]

    uint8_t* ws = (uint8_t*)d_ws;
    f16* xh = (f16*)ws;                                   // 16 MB
    f16* kh_t = (f16*)(ws + (size_t)16 * 1024 * 1024);    // 1 MB
    uint32_t* wt = (uint32_t*)(ws + (size_t)17 * 1024 * 1024);  // 1 MB
    f16* xgh = (f16*)(ws + (size_t)18 * 1024 * 1024);     // 128 MB

    convert_x<<<8192, 256, 0, stream>>>(x, xh);
    transpose_to_f16<<<2048, 256, 0, stream>>>(kern, kh_t);
    transpose_to_f16<<<2048, 256, 0, stream>>>(rk, (f16*)wt);
    gemm_xk<<<dim3(16, 256), 256, 0, stream>>>(xh, kh_t, xgh);
    blstm_rec<<<64, 512, 0, stream>>>(xgh, wt, out);
}